// Round 9
// baseline (218.222 us; speedup 1.0000x reference)
//
#include <hip/hip_runtime.h>
#include <math.h>

#define NN 4096
#define NB 4
#define MSPLIT 16          // column slabs
#define MSLAB 256          // NN / MSPLIT
#define NITER 10

// persistent scratch in module .bss — fully rewritten every call (deterministic)
__device__ __align__(16) float gA [NB * NN];
__device__ __align__(16) float gUx[NB * NN];
__device__ __align__(16) float gUy[NB * NN];
__device__ __align__(16) float gT[NN][12];           // current T vectors
__device__ __align__(16) float gY[MSPLIT][NN][12];   // per-slab partials

__device__ inline unsigned bf16r(float x) {          // RTNE f32 -> bf16 bits
    unsigned u = __float_as_uint(x);
    return (u + 0x7fffu + ((u >> 16) & 1u)) >> 16;
}

// ---- stats + T(iter0) ----
__global__ __launch_bounds__(256) void stats_kernel(const float* __restrict__ dp,
                                                    const float* __restrict__ logits) {
    int i = blockIdx.x * 256 + threadIdx.x;          // 0..16383
    int b = i >> 12, n = i & 4095;
    float x = dp[2 * i], y = dp[2 * i + 1];
    float sq = x * x + y * y;
    float av = expf(-0.5f * sq);
    float inv = 1.0f / sqrtf(sq);
    float uxv = x * inv, uyv = y * inv;
    gA[i] = av; gUx[i] = uxv; gUy[i] = uyv;
    float l = logits[i];
    float mv = 2.0f / (1.0f + expf(-l)) - 1.0f;
    float t0 = av * mv;
    float* t = &gT[n][b * 3];
    t[0] = t0; t[1] = t0 * uxv; t[2] = t0 * uyv;
}

// ---- W_sym = (W+W^T)/2 -> packed bf16 pairs; triangular tile pairs ----
__global__ __launch_bounds__(256) void wsym_kernel(const float* __restrict__ W,
                                                   unsigned* __restrict__ Sb) {
    __shared__ float At[64][65];
    __shared__ float Bt[64][65];
    int idx = blockIdx.x, bi = 0, rem = 64;
    while (idx >= rem) { idx -= rem; ++bi; --rem; }
    int bj = bi + idx;
    int r0 = threadIdx.x >> 4;                       // 0..15
    int c4 = (threadIdx.x & 15) * 4;                 // float col (x4)
#pragma unroll
    for (int i = 0; i < 4; ++i) {
        int r = r0 + i * 16;
        float4 va = *(const float4*)&W[(size_t)(bi * 64 + r) * NN + bj * 64 + c4];
        float4 vb = *(const float4*)&W[(size_t)(bj * 64 + r) * NN + bi * 64 + c4];
        At[r][c4 + 0] = va.x; At[r][c4 + 1] = va.y;
        At[r][c4 + 2] = va.z; At[r][c4 + 3] = va.w;
        Bt[r][c4 + 0] = vb.x; Bt[r][c4 + 1] = vb.y;
        Bt[r][c4 + 2] = vb.z; Bt[r][c4 + 3] = vb.w;
    }
    __syncthreads();
    int tp = threadIdx.x & 31;                       // column-pair index
    int rr = threadIdx.x >> 5;                       // 0..7
#pragma unroll
    for (int i = 0; i < 8; ++i) {
        int r = rr + i * 8;
        int c0 = 2 * tp, c1 = c0 + 1;
        float v0 = 0.5f * (At[r][c0] + Bt[c0][r]);
        float v1 = 0.5f * (At[r][c1] + Bt[c1][r]);
        Sb[(size_t)(bi * 64 + r) * 2048 + bj * 32 + tp] = bf16r(v0) | (bf16r(v1) << 16);
        float u0 = 0.5f * (Bt[r][c0] + At[c0][r]);
        float u1 = 0.5f * (Bt[r][c1] + At[c1][r]);
        Sb[(size_t)(bj * 64 + r) * 2048 + bi * 32 + tp] = bf16r(u0) | (bf16r(u1) << 16);
    }
}

// ---- matvec: gY[by][rows] = Wsym[rows, slab] @ gT[slab]
// grid (128 rowblocks of 32 rows, 16 slabs) = 2048 blocks for TLP.
// wave: 4 groups x 16 lanes; group owns 2 rows; lane s covers m = h*128+s*8+j.
__global__ __launch_bounds__(256, 6) void matvec_kernel(const unsigned* __restrict__ Wb) {
    __shared__ float4 Tp[3][MSLAB];                  // 12 KB
    __shared__ __align__(16) float red[32 * 4 * 12]; // 6 KB

    const int tid = threadIdx.x;
    const int mb = blockIdx.y * MSLAB;
    const int lane = tid & 63, wid = tid >> 6;
    const int g = lane >> 4, s = lane & 15;
    const int row0 = blockIdx.x * 32 + wid * 8 + g * 2;
    const uint4* Wr4 = (const uint4*)(Wb + (size_t)row0 * 2048 + (mb >> 1));

    // weight loads: 2 rows x 2 x dwordx4 = 64 B/thread
    uint4 w[2][2];
#pragma unroll
    for (int r = 0; r < 2; ++r)
#pragma unroll
        for (int h = 0; h < 2; ++h)
            w[r][h] = Wr4[(size_t)r * 512 + h * 16 + s];

    // stage this slab's T into LDS (swizzled float4 index) while loads fly
    {
        const float4* src = (const float4*)&gT[mb + tid][0];
        float4 a = src[0], b = src[1], c = src[2];
        int sm = tid ^ ((tid >> 3) & 7);
        Tp[0][sm] = a; Tp[1][sm] = b; Tp[2][sm] = c;
    }
    __syncthreads();

    float acc[2][12];
#pragma unroll
    for (int r = 0; r < 2; ++r)
#pragma unroll
        for (int c = 0; c < 12; ++c) acc[r][c] = 0.f;

#pragma unroll
    for (int h = 0; h < 2; ++h) {
#pragma unroll
        for (int j = 0; j < 8; ++j) {
            int mj = h * 128 + s * 8 + j;
            int sm = mj ^ ((mj >> 3) & 7);           // 8 bank-groups, 2-way (free)
            float4 t0 = Tp[0][sm], t1 = Tp[1][sm], t2 = Tp[2][sm];
            float tv[12] = {t0.x, t0.y, t0.z, t0.w, t1.x, t1.y, t1.z, t1.w,
                            t2.x, t2.y, t2.z, t2.w};
#pragma unroll
            for (int r = 0; r < 2; ++r) {
                unsigned u = (&w[r][h].x)[j >> 1];
                float wv = __uint_as_float((j & 1) ? (u & 0xffff0000u) : (u << 16));
#pragma unroll
                for (int c = 0; c < 12; ++c) acc[r][c] += wv * tv[c];
            }
        }
    }

    // reduce 16 lanes -> 4: 2 shuffle steps; then 4-way via LDS
#pragma unroll
    for (int mask = 1; mask <= 2; mask <<= 1)
#pragma unroll
        for (int r = 0; r < 2; ++r)
#pragma unroll
            for (int c = 0; c < 12; ++c) acc[r][c] += __shfl_xor(acc[r][c], mask, 64);

    if ((s & 3) == 0) {
        int sub = s >> 2;
#pragma unroll
        for (int r = 0; r < 2; ++r) {
            int rl = wid * 8 + g * 2 + r;
            float4* dst = (float4*)&red[(rl * 4 + sub) * 12];
            dst[0] = make_float4(acc[r][0], acc[r][1], acc[r][2],  acc[r][3]);
            dst[1] = make_float4(acc[r][4], acc[r][5], acc[r][6],  acc[r][7]);
            dst[2] = make_float4(acc[r][8], acc[r][9], acc[r][10], acc[r][11]);
        }
    }
    __syncthreads();

    if (tid < 128) {
        int rl = tid >> 2, c0 = (tid & 3) * 3;
        float s0 = 0.f, s1 = 0.f, s2 = 0.f;
#pragma unroll
        for (int sub = 0; sub < 4; ++sub) {
            const float* p = &red[(rl * 4 + sub) * 12 + c0];
            s0 += p[0]; s1 += p[1]; s2 += p[2];
        }
        int row = blockIdx.x * 32 + rl;
        float* dst = &gY[blockIdx.y][row][c0];
        dst[0] = s0; dst[1] = s1; dst[2] = s2;       // plain stores
    }
}

// ---- update: T <- f(logits + a*(combine gY)) ; 16 blocks, vectorized ----
__global__ __launch_bounds__(256) void update_kernel(const float* __restrict__ logits) {
    int m = blockIdx.x * 256 + threadIdx.x;          // 0..4095
    float S12[12];
#pragma unroll
    for (int c = 0; c < 12; ++c) S12[c] = 0.f;
#pragma unroll 4
    for (int sl = 0; sl < MSPLIT; ++sl) {
        const float4* p = (const float4*)&gY[sl][m][0];
        float4 x = p[0], y = p[1], z = p[2];
        S12[0] += x.x; S12[1] += x.y; S12[2]  += x.z; S12[3]  += x.w;
        S12[4] += y.x; S12[5] += y.y; S12[6]  += y.z; S12[7]  += y.w;
        S12[8] += z.x; S12[9] += z.y; S12[10] += z.z; S12[11] += z.w;
    }
    float vals[12];
#pragma unroll
    for (int b = 0; b < NB; ++b) {
        int idx = b * NN + m;
        float av = gA[idx], uxv = gUx[idx], uyv = gUy[idx];
        float l = logits[idx] +
                  av * (S12[b * 3] - uxv * S12[b * 3 + 1] - uyv * S12[b * 3 + 2]);
        float mv = 2.0f / (1.0f + expf(-l)) - 1.0f;
        float t0 = av * mv;
        vals[b * 3] = t0; vals[b * 3 + 1] = t0 * uxv; vals[b * 3 + 2] = t0 * uyv;
    }
    float4* d = (float4*)&gT[m][0];
    d[0] = make_float4(vals[0], vals[1], vals[2],  vals[3]);
    d[1] = make_float4(vals[4], vals[5], vals[6],  vals[7]);
    d[2] = make_float4(vals[8], vals[9], vals[10], vals[11]);
}

// ---- final: out = logits + a*(S0 - ux*S1 - uy*S2) ----
__global__ __launch_bounds__(256) void final_kernel(const float* __restrict__ logits,
                                                    float* __restrict__ out) {
    int m = blockIdx.x * 256 + threadIdx.x;          // 0..4095
    float S12[12];
#pragma unroll
    for (int c = 0; c < 12; ++c) S12[c] = 0.f;
#pragma unroll 4
    for (int sl = 0; sl < MSPLIT; ++sl) {
        const float4* p = (const float4*)&gY[sl][m][0];
        float4 x = p[0], y = p[1], z = p[2];
        S12[0] += x.x; S12[1] += x.y; S12[2]  += x.z; S12[3]  += x.w;
        S12[4] += y.x; S12[5] += y.y; S12[6]  += y.z; S12[7]  += y.w;
        S12[8] += z.x; S12[9] += z.y; S12[10] += z.z; S12[11] += z.w;
    }
#pragma unroll
    for (int b = 0; b < NB; ++b) {
        int idx = b * NN + m;
        out[idx] = logits[idx] +
                   gA[idx] * (S12[b * 3] - gUx[idx] * S12[b * 3 + 1] - gUy[idx] * S12[b * 3 + 2]);
    }
}

extern "C" void kernel_launch(void* const* d_in, const int* in_sizes, int n_in,
                              void* d_out, int out_size, void* d_ws, size_t ws_size,
                              hipStream_t stream) {
    const float* delta_p = (const float*)d_in[0];   // (4,64,64,2)
    const float* logits  = (const float*)d_in[1];   // (4,4096,1)
    const float* W       = (const float*)d_in[2];   // (1,4096,4096)
    float* out = (float*)d_out;

    unsigned* Wb = (unsigned*)d_ws;                  // 32 MiB packed bf16 Wsym

    stats_kernel<<<64, 256, 0, stream>>>(delta_p, logits);
    wsym_kernel<<<2080, 256, 0, stream>>>(W, Wb);    // 64*65/2 triangular tile pairs

    for (int it = 0; it < NITER; ++it) {
        if (it) update_kernel<<<16, 256, 0, stream>>>(logits);
        matvec_kernel<<<dim3(128, MSPLIT), 256, 0, stream>>>(Wb);
    }
    final_kernel<<<16, 256, 0, stream>>>(logits, out);
}

// Round 10
// 99.711 us; speedup vs baseline: 2.1886x; 2.1886x over previous
//
#include <hip/hip_runtime.h>
#include <math.h>

#define NN 4096
#define NB 4
#define NITER 10
#define ROWS 16            // rows per block
#define TW 512             // 8 waves per block

typedef _Float16 f16x8 __attribute__((ext_vector_type(8)));
typedef float f32x4 __attribute__((ext_vector_type(4)));

// persistent scratch in module .bss — fully rewritten every call (deterministic)
__device__ __align__(16) float gA [NB * NN];
__device__ __align__(16) float gUx[NB * NN];
__device__ __align__(16) float gUy[NB * NN];
__device__ __align__(16) unsigned short gTh[12 * NN];  // T^T as f16: [c][m]

__device__ inline unsigned short f16b(float x) {
    _Float16 h = (_Float16)x;
    return *(unsigned short*)&h;
}
__device__ inline unsigned f16pair(float x, float y) {
    return (unsigned)f16b(x) | ((unsigned)f16b(y) << 16);
}

// ---- stats + T^T(iter0) ----
__global__ __launch_bounds__(256) void stats_kernel(const float* __restrict__ dp,
                                                    const float* __restrict__ logits) {
    int i = blockIdx.x * 256 + threadIdx.x;          // 0..16383
    int b = i >> 12, n = i & 4095;
    float x = dp[2 * i], y = dp[2 * i + 1];
    float sq = x * x + y * y;
    float av = expf(-0.5f * sq);
    float inv = 1.0f / sqrtf(sq);
    float uxv = x * inv, uyv = y * inv;
    gA[i] = av; gUx[i] = uxv; gUy[i] = uyv;
    float l = logits[i];
    float mv = 2.0f / (1.0f + expf(-l)) - 1.0f;
    float t0 = av * mv;
    gTh[(3 * b + 0) * NN + n] = f16b(t0);
    gTh[(3 * b + 1) * NN + n] = f16b(t0 * uxv);
    gTh[(3 * b + 2) * NN + n] = f16b(t0 * uyv);
}

// ---- W_sym = (W+W^T)/2 -> packed f16 pairs; triangular tile pairs ----
__global__ __launch_bounds__(256) void wsym_kernel(const float* __restrict__ W,
                                                   unsigned* __restrict__ Sb) {
    __shared__ float At[64][65];
    __shared__ float Bt[64][65];
    int idx = blockIdx.x, bi = 0, rem = 64;
    while (idx >= rem) { idx -= rem; ++bi; --rem; }
    int bj = bi + idx;
    int r0 = threadIdx.x >> 4;                       // 0..15
    int c4 = (threadIdx.x & 15) * 4;                 // float col (x4)
#pragma unroll
    for (int i = 0; i < 4; ++i) {
        int r = r0 + i * 16;
        float4 va = *(const float4*)&W[(size_t)(bi * 64 + r) * NN + bj * 64 + c4];
        float4 vb = *(const float4*)&W[(size_t)(bj * 64 + r) * NN + bi * 64 + c4];
        At[r][c4 + 0] = va.x; At[r][c4 + 1] = va.y;
        At[r][c4 + 2] = va.z; At[r][c4 + 3] = va.w;
        Bt[r][c4 + 0] = vb.x; Bt[r][c4 + 1] = vb.y;
        Bt[r][c4 + 2] = vb.z; Bt[r][c4 + 3] = vb.w;
    }
    __syncthreads();
    int tp = threadIdx.x & 31;                       // column-pair index
    int rr = threadIdx.x >> 5;                       // 0..7
#pragma unroll
    for (int i = 0; i < 8; ++i) {
        int r = rr + i * 8;
        int c0 = 2 * tp, c1 = c0 + 1;
        float v0 = 0.5f * (At[r][c0] + Bt[c0][r]);
        float v1 = 0.5f * (At[r][c1] + Bt[c1][r]);
        Sb[(size_t)(bi * 64 + r) * 2048 + bj * 32 + tp] = f16pair(v0, v1);
        float u0 = 0.5f * (Bt[r][c0] + At[c0][r]);
        float u1 = 0.5f * (Bt[r][c1] + At[c1][r]);
        Sb[(size_t)(bj * 64 + r) * 2048 + bi * 32 + tp] = f16pair(u0, u1);
    }
}

// ---- fused MFMA matvec + update: block owns 16 rows x full K ----
// E[16 rows][12 cols] = W[rows][:] @ T[:, cols], via mfma_f32_16x16x32_f16.
// A-frag: lane&15 = row, 8 consecutive k (row-major W).  B-frag: lane&15 = c
// (row of T^T), 8 consecutive k (row-major T^T in LDS).  D: col=lane&15,
// row=(lane>>4)*4+reg  [verified m91 mapping].
__global__ __launch_bounds__(TW) void matvec_kernel(const unsigned short* __restrict__ Wh,
    const float* __restrict__ logits, float* __restrict__ out, int last) {
    __shared__ __align__(16) unsigned short Tl[12 * NN];   // 96 KB, swizzled 16B granules
    __shared__ __align__(16) float Ered[8][64][4];         // 8 KB
    __shared__ float El[16][17];

    const int tid = threadIdx.x;

    // ---- stage T^T into LDS: granule (c, koct) at (c*512+koct)^(c&7) ----
#pragma unroll
    for (int c = 0; c < 12; ++c) {
        int koct = tid;                                    // 0..511
        uint4 v = *(const uint4*)(gTh + c * NN + koct * 8);
        int gs = (c * 512 + koct) ^ (c & 7);
        *(uint4*)(Tl + gs * 8) = v;
    }
    __syncthreads();

    const int w = tid >> 6, lane = tid & 63;
    const int mrow = lane & 15, grp = lane >> 4;
    const int row0 = blockIdx.x * ROWS;
    const int kbase = w * 512;                             // K-eighth per wave
    const unsigned short* Wp = Wh + (size_t)(row0 + mrow) * NN + kbase + grp * 8;

    const int cc = mrow;                                   // B col for this lane
    const bool cok = (cc < 12);
    const int gbase = cc * 512 + (kbase >> 3) + grp;

    f32x4 acc = {0.f, 0.f, 0.f, 0.f};
#pragma unroll
    for (int mf = 0; mf < 16; ++mf) {                      // 16 MFMAs, k step 32
        f16x8 a = *(const f16x8*)(Wp + mf * 32);
        f16x8 b = {};
        if (cok) {
            int gs = (gbase + mf * 4) ^ (cc & 7);
            b = *(const f16x8*)(Tl + gs * 8);
        }
        acc = __builtin_amdgcn_mfma_f32_16x16x32_f16(a, b, acc, 0, 0, 0);
    }
    *(f32x4*)Ered[w][lane] = acc;
    __syncthreads();

    // ---- reduce 8 waves, scatter to El[row][col] ----
    if (tid < 64) {
        f32x4 s = {};
#pragma unroll
        for (int ww = 0; ww < 8; ++ww) s += *(const f32x4*)Ered[ww][tid];
        int rr = tid >> 4, c = tid & 15;
#pragma unroll
        for (int r = 0; r < 4; ++r) El[rr * 4 + r][c] = s[r];
    }
    __syncthreads();

    // ---- fused update / final output for this block's 16 rows ----
    if (tid < 64) {
        int b = tid >> 4, r = tid & 15;
        int m = row0 + r, idx = b * NN + m;
        float S0 = El[r][3 * b], S1 = El[r][3 * b + 1], S2 = El[r][3 * b + 2];
        float av = gA[idx], uxv = gUx[idx], uyv = gUy[idx];
        float l = logits[idx] + av * (S0 - uxv * S1 - uyv * S2);
        if (last) {
            out[idx] = l;
        } else {
            float mv = 2.0f / (1.0f + expf(-l)) - 1.0f;
            float t0 = av * mv;
            gTh[(3 * b + 0) * NN + m] = f16b(t0);
            gTh[(3 * b + 1) * NN + m] = f16b(t0 * uxv);
            gTh[(3 * b + 2) * NN + m] = f16b(t0 * uyv);
        }
    }
}

extern "C" void kernel_launch(void* const* d_in, const int* in_sizes, int n_in,
                              void* d_out, int out_size, void* d_ws, size_t ws_size,
                              hipStream_t stream) {
    const float* delta_p = (const float*)d_in[0];   // (4,64,64,2)
    const float* logits  = (const float*)d_in[1];   // (4,4096,1)
    const float* W       = (const float*)d_in[2];   // (1,4096,4096)
    float* out = (float*)d_out;

    unsigned* Wb = (unsigned*)d_ws;                  // 32 MiB packed f16 Wsym
    const unsigned short* Wh = (const unsigned short*)d_ws;

    stats_kernel<<<64, 256, 0, stream>>>(delta_p, logits);
    wsym_kernel<<<2080, 256, 0, stream>>>(W, Wb);    // 64*65/2 triangular tile pairs

    for (int it = 0; it < NITER; ++it)
        matvec_kernel<<<256, TW, 0, stream>>>(Wh, logits, out, it == NITER - 1 ? 1 : 0);
}